// Round 9
// baseline (323.134 us; speedup 1.0000x reference)
//
#include <hip/hip_runtime.h>
#include <hip/hip_bf16.h>
#include <string.h>

// Batched GEMM: out[b,o,f] = sum_i W[b,o,i] * x[b,i,f]
// B=32, M(O)=1024, K(I)=1024, N(F)=2048, fp32 in/out, bf16 MFMA compute.
//
// Round-9: 8-phase-style schedule (m201 port, reg-staged). Geometry from r8:
// 256x256 tile, 512 thr, 8 waves (wave tile 128x64), BK=64, LSTR=68
// (<=2-way banks, 2.1e6 conflicts measured). Each K-step = 4 phases of
// {frag ds_reads + one staging slice -> barrier -> setprio MFMA x16 ->
// barrier}. Staging pipelined: A loads issued P1/consumed P2, B loads
// issued P2/consumed P3 (counted compiler vmcnt, never drain-0 in loop).

typedef float  f32x2 __attribute__((ext_vector_type(2)));
typedef float  f32x4 __attribute__((ext_vector_type(4)));
typedef short  bf16x8 __attribute__((ext_vector_type(8)));
typedef unsigned int u32;

#define BATCH 32
#define MDIM 1024
#define KDIM 1024
#define NDIM 2048
#define BM 256
#define BN 256
#define BK 64
#define NT (KDIM / BK)   // 16 K-steps
#define LSTR 68          // ushorts per LDS row: 64 data + 4 pad (34 banks)

__device__ __forceinline__ u32 cvt2(float a, float b) {
    float2 t; t.x = a; t.y = b;
    __hip_bfloat162 h = __float22bfloat162_rn(t);   // v_cvt_pk_bf16_f32 (RTNE)
    u32 r; memcpy(&r, &h, 4);
    return r;
}

// Barrier that does NOT drain vmcnt: LDS visibility only.
__device__ __forceinline__ void lds_barrier() {
    asm volatile("s_waitcnt lgkmcnt(0)" ::: "memory");
    __builtin_amdgcn_s_barrier();
    asm volatile("" ::: "memory");
}

__global__ __launch_bounds__(512, 2) void bgemm_bf16_kernel(
    const float* __restrict__ x, const float* __restrict__ w,
    float* __restrict__ out)
{
    __shared__ unsigned short Ab[2][BM * LSTR];   // W tile  [m][k]
    __shared__ unsigned short Bb[2][BN * LSTR];   // x tile^T [n][k]

    // ---- XCD-chunked bijective block swizzle (1024 blocks, 1024%8==0) ----
    const int bid  = blockIdx.x;
    const int lbid = (bid & 7) * 128 + (bid >> 3);
    const int bx = lbid & 7;          // n-tile
    const int by = (lbid >> 3) & 3;   // m-tile
    const int bz = lbid >> 5;         // batch

    const int tid = threadIdx.x;
    const int m0  = by * BM;
    const int n0  = bx * BN;

    const int lane = tid & 63;
    const int wid  = tid >> 6;
    const int wm   = (wid >> 2) * 128;   // wave tile 128x64
    const int wn   = (wid & 3)  * 64;
    const int l15  = lane & 15;
    const int kg8  = (lane >> 4) * 8;

    const float* Ag = w + (size_t)bz * MDIM * KDIM + (size_t)m0 * KDIM;
    const float* Bg = x + (size_t)bz * KDIM * NDIM + n0;
    float*       Cg = out + (size_t)bz * MDIM * NDIM + (size_t)m0 * NDIM + n0;

    // ---- A staging map: thread -> rows (tid>>4)+32i (i=0..7), f32x4 col tid&15
    const int a_k4 = tid & 15;
    const int a_m0 = tid >> 4;           // 0..31
    int a_idx[8];
    #pragma unroll
    for (int i = 0; i < 8; ++i)
        a_idx[i] = (a_m0 + 32 * i) * LSTR + 4 * a_k4;
    // ---- B staging map: k rows b_k0+j (+32), n cols 2*(tid&127)+c ----
    const int bn0  = 2 * (tid & 127);
    const int b_k0 = 8 * (tid >> 7);     // 0,8,16,24
    int b_idx[2];
    #pragma unroll
    for (int c = 0; c < 2; ++c)
        b_idx[c] = (bn0 + c) * LSTR + b_k0;
    // ---- frag read addrs (add +32 for kk1) ----
    int rd_a[8], rd_b[4];
    #pragma unroll
    for (int mi = 0; mi < 8; ++mi)
        rd_a[mi] = (wm + mi * 16 + l15) * LSTR + kg8;
    #pragma unroll
    for (int ni = 0; ni < 4; ++ni)
        rd_b[ni] = (wn + ni * 16 + l15) * LSTR + kg8;

    const float* Ap = Ag + (size_t)a_m0 * KDIM + 4 * a_k4;
    const float* Bp = Bg + (size_t)b_k0 * NDIM + bn0;

    f32x4 acc[8][4];
    #pragma unroll
    for (int i = 0; i < 8; ++i)
        #pragma unroll
        for (int j = 0; j < 4; ++j)
            acc[i][j] = f32x4{0.f, 0.f, 0.f, 0.f};

    f32x4 aav[8];    // A K-step in flight (32 f32)
    f32x2 bbv[16];   // B K-step in flight (32 f32)

    auto load_A = [&](int kt) {
        #pragma unroll
        for (int i = 0; i < 8; ++i)
            aav[i] = *reinterpret_cast<const f32x4*>(
                Ap + (size_t)(32 * i) * KDIM + kt);
    };
    auto load_B = [&](int kt) {
        #pragma unroll
        for (int j = 0; j < 8; ++j) {
            bbv[j]     = *reinterpret_cast<const f32x2*>(
                Bp + (size_t)(kt + j) * NDIM);
            bbv[j + 8] = *reinterpret_cast<const f32x2*>(
                Bp + (size_t)(kt + 32 + j) * NDIM);
        }
    };
    auto stage_A = [&](int s) {
        #pragma unroll
        for (int i = 0; i < 8; ++i) {
            uint2 v = make_uint2(cvt2(aav[i][0], aav[i][1]),
                                 cvt2(aav[i][2], aav[i][3]));
            *reinterpret_cast<uint2*>(&Ab[s][a_idx[i]]) = v;   // b64
        }
    };
    auto stage_B = [&](int s) {
        #pragma unroll
        for (int c = 0; c < 2; ++c) {
            uint4 v0 = make_uint4(cvt2(bbv[0][c], bbv[1][c]),
                                  cvt2(bbv[2][c], bbv[3][c]),
                                  cvt2(bbv[4][c], bbv[5][c]),
                                  cvt2(bbv[6][c], bbv[7][c]));
            *reinterpret_cast<uint4*>(&Bb[s][b_idx[c]]) = v0;      // b128 kk0
            uint4 v1 = make_uint4(cvt2(bbv[8][c],  bbv[9][c]),
                                  cvt2(bbv[10][c], bbv[11][c]),
                                  cvt2(bbv[12][c], bbv[13][c]),
                                  cvt2(bbv[14][c], bbv[15][c]));
            *reinterpret_cast<uint4*>(&Bb[s][b_idx[c] + 32]) = v1; // b128 kk1
        }
    };
    auto mfma4 = [&](int mb, const bf16x8* afr, const bf16x8* bfr) {
        __builtin_amdgcn_s_setprio(1);
        #pragma unroll
        for (int mi = 0; mi < 4; ++mi)
            #pragma unroll
            for (int ni = 0; ni < 4; ++ni)
                acc[mb + mi][ni] = __builtin_amdgcn_mfma_f32_16x16x32_bf16(
                    afr[mi], bfr[ni], acc[mb + mi][ni], 0, 0, 0);
        __builtin_amdgcn_s_setprio(0);
    };

    // ---- prologue: stage tile 0 ----
    load_A(0);
    load_B(0);
    stage_A(0);
    stage_B(0);
    lds_barrier();

    // ---- main loop: 4 phases per K-step ----
    for (int t = 0; t < NT - 1; ++t) {
        const int cur = t & 1;
        const int nxt = cur ^ 1;
        const int ktn = (t + 1) * BK;
        bf16x8 afr[4], bfr[4];

        // ===== P1: frags(A mi0-3, B; kk0) + issue A(t+1) =====
        #pragma unroll
        for (int ni = 0; ni < 4; ++ni)
            bfr[ni] = *reinterpret_cast<const bf16x8*>(&Bb[cur][rd_b[ni]]);
        #pragma unroll
        for (int mi = 0; mi < 4; ++mi)
            afr[mi] = *reinterpret_cast<const bf16x8*>(&Ab[cur][rd_a[mi]]);
        load_A(ktn);
        lds_barrier();
        mfma4(0, afr, bfr);
        lds_barrier();

        // ===== P2: frags(A mi4-7 kk0) + cvt/write A(t+1) + issue B(t+1) =====
        #pragma unroll
        for (int mi = 0; mi < 4; ++mi)
            afr[mi] = *reinterpret_cast<const bf16x8*>(&Ab[cur][rd_a[mi + 4]]);
        stage_A(nxt);
        load_B(ktn);
        lds_barrier();
        mfma4(4, afr, bfr);
        lds_barrier();

        // ===== P3: frags(A mi0-3, B; kk1) + cvt/write B(t+1) =====
        #pragma unroll
        for (int ni = 0; ni < 4; ++ni)
            bfr[ni] = *reinterpret_cast<const bf16x8*>(&Bb[cur][rd_b[ni] + 32]);
        #pragma unroll
        for (int mi = 0; mi < 4; ++mi)
            afr[mi] = *reinterpret_cast<const bf16x8*>(&Ab[cur][rd_a[mi] + 32]);
        stage_B(nxt);
        lds_barrier();
        mfma4(0, afr, bfr);
        lds_barrier();

        // ===== P4: frags(A mi4-7 kk1), no staging =====
        #pragma unroll
        for (int mi = 0; mi < 4; ++mi)
            afr[mi] = *reinterpret_cast<const bf16x8*>(&Ab[cur][rd_a[mi + 4] + 32]);
        lds_barrier();
        mfma4(4, afr, bfr);
        lds_barrier();
    }

    // ---- tail: tile NT-1, no staging ----
    {
        const int cur = (NT - 1) & 1;
        #pragma unroll
        for (int kk = 0; kk < 2; ++kk) {
            bf16x8 bfr[4];
            #pragma unroll
            for (int ni = 0; ni < 4; ++ni)
                bfr[ni] = *reinterpret_cast<const bf16x8*>(
                    &Bb[cur][rd_b[ni] + 32 * kk]);
            #pragma unroll
            for (int mi = 0; mi < 8; ++mi) {
                bf16x8 af = *reinterpret_cast<const bf16x8*>(
                    &Ab[cur][rd_a[mi] + 32 * kk]);
                #pragma unroll
                for (int ni = 0; ni < 4; ++ni)
                    acc[mi][ni] = __builtin_amdgcn_mfma_f32_16x16x32_bf16(
                        af, bfr[ni], acc[mi][ni], 0, 0, 0);
            }
        }
    }

    // ---- C store: D layout col=lane&15, row=(lane>>4)*4+reg ----
    const int rbase = (lane >> 4) * 4;
    #pragma unroll
    for (int mi = 0; mi < 8; ++mi) {
        #pragma unroll
        for (int ni = 0; ni < 4; ++ni) {
            int n  = wn + ni * 16 + l15;
            int mb = wm + mi * 16 + rbase;
            #pragma unroll
            for (int r = 0; r < 4; ++r)
                Cg[(size_t)(mb + r) * NDIM + n] = acc[mi][ni][r];
        }
    }
}

extern "C" void kernel_launch(void* const* d_in, const int* in_sizes, int n_in,
                              void* d_out, int out_size, void* d_ws, size_t ws_size,
                              hipStream_t stream) {
    const float* x = (const float*)d_in[0];   // [32][1024][2048]
    const float* w = (const float*)d_in[1];   // [32][1024][1024]
    float* out = (float*)d_out;               // [32][1024][2048]
    const int nblocks = (NDIM / BN) * (MDIM / BM) * BATCH;  // 8*4*32 = 1024
    bgemm_bf16_kernel<<<dim3(nblocks), dim3(512), 0, stream>>>(x, w, out);
}